// Round 5
// baseline (498.985 us; speedup 1.0000x reference)
//
#include <hip/hip_runtime.h>
#include <math.h>
#include <stdint.h>

#define TN   4096
#define DI   1024
#define BSZ  60
#define LOGT 8.317766166719343f
#define EPSV 1e-12f

typedef __bf16 bf16;
typedef bf16  bf16x4 __attribute__((ext_vector_type(4)));
typedef bf16  bf16x8 __attribute__((ext_vector_type(8)));
typedef float f32x4  __attribute__((ext_vector_type(4)));

#define AS1 __attribute__((address_space(1)))
#define AS3 __attribute__((address_space(3)))

__device__ __forceinline__ void gload16(const void* g, void* l){
  __builtin_amdgcn_global_load_lds((AS1 unsigned int*)(uintptr_t)g,
                                   (AS3 unsigned int*)(unsigned int)(uintptr_t)l,
                                   16, 0, 0);
}

// ---------------- reductions ----------------
__device__ __forceinline__ float wsum(float v){
#pragma unroll
  for (int o = 32; o >= 1; o >>= 1) v += __shfl_xor(v, o);
  return v;
}
__device__ __forceinline__ float wmaxr(float v){
#pragma unroll
  for (int o = 32; o >= 1; o >>= 1) v = fmaxf(v, __shfl_xor(v, o));
  return v;
}
__device__ __forceinline__ float bsum(float v, float* sh){
  v = wsum(v);
  if ((threadIdx.x & 63) == 0) sh[threadIdx.x >> 6] = v;
  __syncthreads();
  float r = sh[0] + sh[1] + sh[2] + sh[3];
  __syncthreads();
  return r;
}
__device__ __forceinline__ float bmaxr(float v, float* sh){
  v = wmaxr(v);
  if ((threadIdx.x & 63) == 0) sh[threadIdx.x >> 6] = v;
  __syncthreads();
  float r = fmaxf(fmaxf(sh[0], sh[1]), fmaxf(sh[2], sh[3]));
  __syncthreads();
  return r;
}

// ---------------- prep: xu = normalize(x); xs = [hi|lo] bf16 split (stride 2048) ----------------
__global__ __launch_bounds__(256) void k_prep(const float* __restrict__ x,
                                              float* __restrict__ xu,
                                              bf16* __restrict__ xs){
  __shared__ float sh[4];
  int r = blockIdx.x, tid = threadIdx.x;
  float4 v = ((const float4*)(x + (size_t)r * DI))[tid];
  float ss = v.x*v.x + v.y*v.y + v.z*v.z + v.w*v.w;
  ss = bsum(ss, sh);
  float inv = 1.f / fmaxf(sqrtf(ss), EPSV);
  float4 o = {v.x*inv, v.y*inv, v.z*inv, v.w*inv};
  ((float4*)(xu + (size_t)r * DI))[tid] = o;
  bf16 h0 = (bf16)v.x, h1 = (bf16)v.y, h2 = (bf16)v.z, h3 = (bf16)v.w;
  bf16x4 hv = {h0, h1, h2, h3};
  bf16x4 lv = {(bf16)(v.x-(float)h0), (bf16)(v.y-(float)h1),
               (bf16)(v.z-(float)h2), (bf16)(v.w-(float)h3)};
  *(bf16x4*)&xs[(size_t)r * 2048 + tid * 4]        = hv;
  *(bf16x4*)&xs[(size_t)r * 2048 + 1024 + tid * 4] = lv;
}

// ---------------- fused weight transposes ----------------
// z=0..2: W{q,k,v} -> Ws rows z*1024.. as [hi|lo] stride 2048.  z=3: Wout[:DI] -> Woth.
__global__ __launch_bounds__(256) void k_trw(const float* __restrict__ W0,
                                             const float* __restrict__ W1,
                                             const float* __restrict__ W2,
                                             const float* __restrict__ W3,
                                             bf16* __restrict__ Ws,
                                             bf16* __restrict__ woth){
  __shared__ float t[64][65];
  int z = blockIdx.z;
  const float* src = (z==0) ? W0 : (z==1) ? W1 : (z==2) ? W2 : W3;
  int c0 = blockIdx.x * 64, r0 = blockIdx.y * 64;
  int tid = threadIdx.x;
  int lr = tid >> 4, lc = (tid & 15) * 4;
#pragma unroll
  for (int p = 0; p < 4; ++p){
    int r = lr + p * 16;
    float4 v = *(const float4*)&src[(size_t)(r0 + r) * DI + c0 + lc];
    t[r][lc+0] = v.x; t[r][lc+1] = v.y; t[r][lc+2] = v.z; t[r][lc+3] = v.w;
  }
  __syncthreads();
#pragma unroll
  for (int p = 0; p < 4; ++p){
    int c = lr + p * 16;
    float v0 = t[lc+0][c], v1 = t[lc+1][c], v2 = t[lc+2][c], v3 = t[lc+3][c];
    bf16 h0 = (bf16)v0, h1 = (bf16)v1, h2 = (bf16)v2, h3 = (bf16)v3;
    bf16x4 hv = {h0, h1, h2, h3};
    if (z < 3){
      bf16* dh = Ws + (size_t)(z * DI + c0 + c) * 2048 + r0 + lc;
      *(bf16x4*)dh = hv;
      bf16x4 lv = {(bf16)(v0-(float)h0), (bf16)(v1-(float)h1),
                   (bf16)(v2-(float)h2), (bf16)(v3-(float)h3)};
      *(bf16x4*)(dh + 1024) = lv;
    } else {
      *(bf16x4*)&woth[(size_t)(c0 + c) * DI + r0 + lc] = hv;
    }
  }
}

// ---------------- transpose fp32 [R][C] -> bf16 [C][R] ----------------
__global__ __launch_bounds__(256) void k_trx(const float* __restrict__ in,
                                             bf16* __restrict__ outh,
                                             int R, int C){
  __shared__ float t[64][65];
  int c0 = blockIdx.x * 64, r0 = blockIdx.y * 64;
  int tid = threadIdx.x;
  int lr = tid >> 4, lc = (tid & 15) * 4;
#pragma unroll
  for (int p = 0; p < 4; ++p){
    int r = lr + p * 16;
    float4 v = *(const float4*)&in[(size_t)(r0 + r) * C + c0 + lc];
    t[r][lc+0] = v.x; t[r][lc+1] = v.y; t[r][lc+2] = v.z; t[r][lc+3] = v.w;
  }
  __syncthreads();
#pragma unroll
  for (int p = 0; p < 4; ++p){
    int c = lr + p * 16;
    bf16x4 hv = {(bf16)t[lc+0][c], (bf16)t[lc+1][c], (bf16)t[lc+2][c], (bf16)t[lc+3][c]};
    *(bf16x4*)&outh[(size_t)(c0 + c) * R + r0 + lc] = hv;
  }
}

// ---------------- column sums of xu ----------------
__global__ __launch_bounds__(256) void k_colsum1(const float* __restrict__ xu,
                                                 float* __restrict__ part){
  int c  = blockIdx.x * 256 + threadIdx.x;
  int r0 = blockIdx.y * 128;
  float s = 0.f;
  for (int r = r0; r < r0 + 128; ++r) s += xu[(size_t)r * DI + c];
  part[(size_t)blockIdx.y * DI + c] = s;
}
__global__ __launch_bounds__(256) void k_colsum2(const float* __restrict__ part,
                                                 float* __restrict__ stot){
  int c = blockIdx.x * 256 + threadIdx.x;
  float s = 0.f;
  for (int b = 0; b < 32; ++b) s += part[(size_t)b * DI + c];
  stot[c] = s;
}

// ================= 256x256 pipelined split-3 MFMA GEMM =================
// A',B' are [rows][2048] = [hi|lo]; K_eff = 3072 via K-tile remap (BK=32, 96 tiles):
//   t<32: Ah*Bh   t<64: Ah*Bl   t<96: Al*Bh
// EPI 0: C fp32 [M][TN] (E).  EPI 1: QKV epilogue (Q,K -> hi/lo split; V -> fp32).
template<int EPI>
__global__ __launch_bounds__(512, 2) void k_mfma256(
    const bf16* __restrict__ A, const bf16* __restrict__ B,
    float* __restrict__ C, bf16* __restrict__ Qs, bf16* __restrict__ Ks,
    float* __restrict__ Vb)
{
  __shared__ alignas(16) bf16 lds[32768];   // 64KB: [A0 16K][B0 16K][A1 16K][B1 16K]
  const int tid = threadIdx.x, wid = tid >> 6, lane = tid & 63;
  const int l15 = lane & 15, kb = lane >> 4;
  const int wm = wid >> 2, wn = wid & 3;
  const int row0 = blockIdx.y * 256, col0 = blockIdx.x * 256;

  f32x4 acc[8][4];
  const f32x4 zero = {0.f, 0.f, 0.f, 0.f};
#pragma unroll
  for (int m = 0; m < 8; ++m)
#pragma unroll
    for (int n = 0; n < 4; ++n) acc[m][n] = zero;

  const bf16* Arow = A + (size_t)row0 * 2048;
  const bf16* Brow = B + (size_t)col0 * 2048;

  // prologue: stage tile 0 into buf 0
#pragma unroll
  for (int i = 0; i < 2; ++i){
    int U = i * 512 + tid, r = U >> 2, cg = (U & 3) ^ ((r >> 1) & 3);
    gload16(Arow + (size_t)r * 2048 + cg * 8, lds + (i * 512 + wid * 64) * 8);
    gload16(Brow + (size_t)r * 2048 + cg * 8, lds + 8192 + (i * 512 + wid * 64) * 8);
  }

  for (int t = 0; t < 96; ++t){
    __syncthreads();            // implicit vmcnt(0): tile-t loads landed; prev reads done
    const int buf = t & 1;
    const bf16* sA = lds + buf * 16384;
    const bf16* sB = sA + 8192;

    if (t + 1 < 96){            // issue next tile EARLY (hides latency under this tile's MFMA)
      const int t1 = t + 1;
      const int offA = ((t1 & 31) << 5) + ((t1 >= 64) ? 1024 : 0);
      const int offB = ((t1 & 31) << 5) + ((t1 >= 32 && t1 < 64) ? 1024 : 0);
      bf16* dA = lds + (buf ^ 1) * 16384;
      bf16* dB = dA + 8192;
#pragma unroll
      for (int i = 0; i < 2; ++i){
        int U = i * 512 + tid, r = U >> 2, cg = (U & 3) ^ ((r >> 1) & 3);
        gload16(Arow + (size_t)r * 2048 + offA + cg * 8, dA + (i * 512 + wid * 64) * 8);
        gload16(Brow + (size_t)r * 2048 + offB + cg * 8, dB + (i * 512 + wid * 64) * 8);
      }
    }

    bf16x8 af[8];
#pragma unroll
    for (int m = 0; m < 8; ++m){
      int r = wm * 128 + m * 16 + l15;
      af[m] = *(const bf16x8*)(sA + r * 32 + ((kb ^ ((r >> 1) & 3)) << 3));
    }
#pragma unroll
    for (int half = 0; half < 2; ++half){
      bf16x8 bfr[2];
#pragma unroll
      for (int n = 0; n < 2; ++n){
        int r = wn * 64 + (half * 2 + n) * 16 + l15;
        bfr[n] = *(const bf16x8*)(sB + r * 32 + ((kb ^ ((r >> 1) & 3)) << 3));
      }
      __builtin_amdgcn_s_setprio(1);
#pragma unroll
      for (int m = 0; m < 8; ++m){
        acc[m][half*2+0] = __builtin_amdgcn_mfma_f32_16x16x32_bf16(af[m], bfr[0], acc[m][half*2+0], 0, 0, 0);
        acc[m][half*2+1] = __builtin_amdgcn_mfma_f32_16x16x32_bf16(af[m], bfr[1], acc[m][half*2+1], 0, 0, 0);
      }
      __builtin_amdgcn_s_setprio(0);
    }
  }

  const int l4 = lane >> 4;
#pragma unroll
  for (int m = 0; m < 8; ++m){
#pragma unroll
    for (int n = 0; n < 4; ++n){
#pragma unroll
      for (int r = 0; r < 4; ++r){
        int grow = row0 + wm * 128 + m * 16 + l4 * 4 + r;
        int gcol = col0 + wn * 64 + n * 16 + l15;
        float v = acc[m][n][r];
        if constexpr (EPI == 0){
          C[(size_t)grow * TN + gcol] = v;
        } else {
          if (blockIdx.x < 4){
            bf16 h = (bf16)v;
            Qs[(size_t)grow * 2048 + gcol]        = h;
            Qs[(size_t)grow * 2048 + 1024 + gcol] = (bf16)(v - (float)h);
          } else if (blockIdx.x < 8){
            int cc = gcol - 1024;
            bf16 h = (bf16)v;
            Ks[(size_t)grow * 2048 + cc]        = h;
            Ks[(size_t)grow * 2048 + 1024 + cc] = (bf16)(v - (float)h);
          } else {
            Vb[(size_t)grow * DI + (gcol - 2048)] = v;
          }
        }
      }
    }
  }
}

// ---------------- 128x128 MFMA GEMM (plain bf16): C = A[M,K] * Bt[N,K]^T ----------------
// EPI: 0 = fp32 C;  2 = fp32 C + (ev[row]/max(sums[0],eps))*W12[col] + dv[row]*W12[DI+col]
template<int EPI>
__global__ __launch_bounds__(256) void k_mfma(
    const bf16* __restrict__ Ah, const bf16* __restrict__ Bh,
    int lda, int ldb, int N, int K,
    float* __restrict__ C,
    const float* __restrict__ ev, const float* __restrict__ dv,
    const float* __restrict__ sums, const float* __restrict__ W12)
{
  __shared__ alignas(16) bf16 lds[8192];
  bf16* sAh = lds;
  bf16* sBh = lds + 4096;

  const int tid = threadIdx.x;
  const int wid = tid >> 6;
  const int lane = tid & 63;
  const int row0 = blockIdx.y * 128, col0 = blockIdx.x * 128;
  const int wr = (wid >> 1) * 64, wc = (wid & 1) * 64;
  const int l15 = lane & 15, kb = lane >> 4;

  const int u0 = tid,       r0u = u0 >> 2, k0u = (u0 & 3) ^ ((r0u >> 1) & 3);
  const int u1 = tid + 256, r1u = u1 >> 2, k1u = (u1 & 3) ^ ((r1u >> 1) & 3);
  const int d0 = wid * 64 * 8;
  const int d1 = (256 + wid * 64) * 8;

  f32x4 acc[4][4];
  const f32x4 zero = {0.f, 0.f, 0.f, 0.f};
#pragma unroll
  for (int m = 0; m < 4; ++m)
#pragma unroll
    for (int n = 0; n < 4; ++n) acc[m][n] = zero;

  const bf16* pAh = Ah + (size_t)row0 * lda;
  const bf16* pBh = Bh + (size_t)col0 * ldb;

  for (int k0 = 0; k0 < K; k0 += 32){
    gload16(pAh + k0 + (size_t)r0u * lda + k0u * 8, sAh + d0);
    gload16(pAh + k0 + (size_t)r1u * lda + k1u * 8, sAh + d1);
    gload16(pBh + k0 + (size_t)r0u * ldb + k0u * 8, sBh + d0);
    gload16(pBh + k0 + (size_t)r1u * ldb + k1u * 8, sBh + d1);
    __syncthreads();

    bf16x8 bh[4];
#pragma unroll
    for (int n = 0; n < 4; ++n){
      int rr = wc + n * 16 + l15;
      int ss = kb ^ ((rr >> 1) & 3);
      bh[n] = *(const bf16x8*)(sBh + (rr * 4 + ss) * 8);
    }
#pragma unroll
    for (int m = 0; m < 4; ++m){
      int rr = wr + m * 16 + l15;
      int ss = kb ^ ((rr >> 1) & 3);
      bf16x8 ah = *(const bf16x8*)(sAh + (rr * 4 + ss) * 8);
#pragma unroll
      for (int n = 0; n < 4; ++n)
        acc[m][n] = __builtin_amdgcn_mfma_f32_16x16x32_bf16(ah, bh[n], acc[m][n], 0, 0, 0);
    }
    __syncthreads();
  }

  const int l4 = lane >> 4;
#pragma unroll
  for (int m = 0; m < 4; ++m){
#pragma unroll
    for (int n = 0; n < 4; ++n){
#pragma unroll
      for (int r = 0; r < 4; ++r){
        int row = row0 + wr + m * 16 + l4 * 4 + r;
        int col = col0 + wc + n * 16 + l15;
        float v = acc[m][n][r];
        if constexpr (EPI == 0){
          C[(size_t)row * N + col] = v;
        } else {
          float en = ev[row] / fmaxf(sums[0], EPSV);
          v += en * W12[col] + dv[row] * W12[DI + col];
          C[(size_t)row * N + col] = v;
        }
      }
    }
  }
}

// ---------------- row stats over E -> P bf16 + Hraw/Hwin/divh ----------------
__global__ __launch_bounds__(256) void k_rowstats(const float* __restrict__ E,
                                                  bf16* __restrict__ Pbf,
                                                  float* __restrict__ Hraw,
                                                  float* __restrict__ Hwin,
                                                  float* __restrict__ divh){
  __shared__ float sh[4];
  int i = blockIdx.x, tid = threadIdx.x;
  const float4* row4 = (const float4*)(E + (size_t)i * TN);
  float4 v[4];
#pragma unroll
  for (int k = 0; k < 4; ++k) v[k] = row4[tid + k * 256];

  int b0 = (i / BSZ) * BSZ;
  int b1 = min(b0 + BSZ, TN);
  int nb = b1 - b0;
  float ewin = -3.4e38f;
  if (tid < 64 && tid < nb) ewin = E[(size_t)i * TN + b0 + tid];

  float mx = -3.4e38f;
#pragma unroll
  for (int k = 0; k < 4; ++k)
    mx = fmaxf(mx, fmaxf(fmaxf(v[k].x, v[k].y), fmaxf(v[k].z, v[k].w)));
  mx = bmaxr(mx, sh);

  float s1 = 0.f, s2 = 0.f;
#pragma unroll
  for (int k = 0; k < 4; ++k){
    float e[4] = {v[k].x, v[k].y, v[k].z, v[k].w};
#pragma unroll
    for (int q = 0; q < 4; ++q){
      float t = e[q] - mx; float w = __expf(t); s1 += w; s2 += w * t;
    }
  }
  s1 = bsum(s1, sh);
  s2 = bsum(s2, sh);
  float rl = 1.f / s1;
  float H  = (__logf(s1) - s2 * rl) / LOGT;

  if (tid < 64){
    float mw = wmaxr(ewin);
    mw = fmaxf(mw, 0.f);
    float t = ewin - mw;
    float w  = (tid < nb) ? __expf(t) : 0.f;
    float wt = (tid < nb) ? w * t     : 0.f;
    float z  = __expf(-mw);
    float s1w = wsum(w)  + (float)(TN - nb) * z;
    float s2w = wsum(wt) + (float)(TN - nb) * z * (-mw);
    if (tid == 0) Hwin[i] = (__logf(s1w) - s2w / s1w) / LOGT;
  }

  float ld = 0.f;
#pragma unroll
  for (int k = 0; k < 4; ++k){
    float e[4] = {v[k].x, v[k].y, v[k].z, v[k].w};
    float p[4];
#pragma unroll
    for (int q = 0; q < 4; ++q){
      p[q] = __expf(e[q] - mx) * rl;
      ld += log1pf(-p[q]);
    }
    bf16x4 pb = {(bf16)p[0], (bf16)p[1], (bf16)p[2], (bf16)p[3]};
    *(bf16x4*)&Pbf[(size_t)i * TN + (size_t)(k * 256 + tid) * 4] = pb;
  }
  ld = bsum(ld, sh);
  if (tid == 0){
    Hraw[i] = H;
    divh[i] = __expf(ld);
  }
}

// ---------------- L1 sums ----------------
__global__ __launch_bounds__(256) void k_sumvec(const float* __restrict__ Hraw,
                                                const float* __restrict__ divh,
                                                float* __restrict__ sums){
  __shared__ float sh[4];
  int tid = threadIdx.x;
  float a = 0.f, b = 0.f;
  for (int i = tid; i < TN; i += 256){ a += fabsf(Hraw[i]); b += fabsf(divh[i]); }
  a = bsum(a, sh);
  b = bsum(b, sh);
  if (tid == 0){ sums[0] = a; sums[1] = b; }
}

// ---------------- dep_factor ----------------
__global__ __launch_bounds__(256) void k_dep(const float* __restrict__ xu,
                                             const float* __restrict__ stot,
                                             const float* __restrict__ cb,
                                             const bf16* __restrict__ Pbf,
                                             float* __restrict__ dep){
  __shared__ float xi[DI];
  __shared__ float sh[4];
  __shared__ float accs[4][3];
  int i = blockIdx.x, tid = threadIdx.x;
  float4 v = ((const float4*)(xu + (size_t)i * DI))[tid];
  ((float4*)xi)[tid] = v;
  float4 s4 = ((const float4*)stot)[tid];
  float4 c4 = ((const float4*)(cb + (size_t)i * DI))[tid];
  float pa = v.x*s4.x + v.y*s4.y + v.z*s4.z + v.w*s4.w;
  float pb = v.x*c4.x + v.y*c4.y + v.z*c4.z + v.w*c4.w;
  float sim_all    = bsum(pa, sh);
  float simatt_all = bsum(pb, sh);

  int b0 = (i / BSZ) * BSZ;
  int b1 = min(b0 + BSZ, TN);
  int nb = b1 - b0;
  int wid = tid >> 6, lane = tid & 63;
  float att_in = 0.f, sim_in = 0.f, simatt_in = 0.f;
  for (int j = b0 + wid; j < b1; j += 4){
    const float* xj = xu + (size_t)j * DI;
    float s = 0.f;
#pragma unroll
    for (int d = 0; d < 16; ++d) s += xi[d * 64 + lane] * xj[d * 64 + lane];
#pragma unroll
    for (int o = 32; o >= 1; o >>= 1) s += __shfl_xor(s, o);
    float att = (float)Pbf[(size_t)i * TN + j];
    att_in += att; sim_in += s; simatt_in += att * s;
  }
  if (lane == 0){ accs[wid][0] = att_in; accs[wid][1] = sim_in; accs[wid][2] = simatt_in; }
  __syncthreads();
  if (tid == 0){
    float a = 0.f, si = 0.f, sa = 0.f;
#pragma unroll
    for (int w = 0; w < 4; ++w){ a += accs[w][0]; si += accs[w][1]; sa += accs[w][2]; }
    float num = (1.f - a) - (simatt_all - sa);
    float den = (float)(TN - nb) - (sim_all - si);
    dep[i] = num / den;
  }
}

// ---------------- epi: att row fill + y_mid, one block per row ----------------
__global__ __launch_bounds__(256) void k_epi(const bf16* __restrict__ Pbf,
                                             const float* __restrict__ dep,
                                             const float* __restrict__ V,
                                             float* __restrict__ att,
                                             bf16* __restrict__ ym){
  __shared__ float w[64];
  int i = blockIdx.x, tid = threadIdx.x;
  int b0 = (i / BSZ) * BSZ;
  int b1 = min(b0 + BSZ, TN);
  int nb = b1 - b0;
  if (tid < nb) w[tid] = (float)Pbf[(size_t)i * TN + b0 + tid] + dep[b0 + tid];
  __syncthreads();

#pragma unroll
  for (int g = 0; g < 4; ++g){
    int c = g * 1024 + tid * 4;
    size_t base = (size_t)i * TN + c;
    float4 av = {0.f, 0.f, 0.f, 0.f};
    if (c + 3 >= b0 && c < b1){
      float t2[4];
#pragma unroll
      for (int q = 0; q < 4; ++q){
        int j = c + q;
        t2[q] = (j >= b0 && j < b1) ? w[j - b0] : 0.f;
      }
      av.x = t2[0]; av.y = t2[1]; av.z = t2[2]; av.w = t2[3];
    }
    *(float4*)&att[base] = av;
  }

  float4 a = {0.f, 0.f, 0.f, 0.f};
  for (int jj = 0; jj < nb; ++jj){
    float wv = w[jj];
    float4 vv = ((const float4*)(V + (size_t)(b0 + jj) * DI))[tid];
    a.x += wv * vv.x; a.y += wv * vv.y; a.z += wv * vv.z; a.w += wv * vv.w;
  }
  bf16x4 o = {(bf16)a.x, (bf16)a.y, (bf16)a.z, (bf16)a.w};
  *(bf16x4*)&ym[(size_t)i * DI + (size_t)tid * 4] = o;
}

// ---------------- ent/div fill (runs LAST; clobbers all big scratch) ----------------
__global__ __launch_bounds__(256) void k_fill_entdiv(const float* __restrict__ Hw,
                                                     const float* __restrict__ divh,
                                                     const float* __restrict__ sums,
                                                     float* __restrict__ ent,
                                                     float* __restrict__ div_){
  int i = blockIdx.x, tid = threadIdx.x;
  float rs = 1.f / sums[1];
#pragma unroll
  for (int g = 0; g < 4; ++g){
    int c = g * 1024 + tid * 4;
    size_t base = (size_t)i * TN + c;
    float4 hv = *(const float4*)&Hw[c];
    float4 dv = *(const float4*)&divh[c];
    float4 dn = {dv.x*rs, dv.y*rs, dv.z*rs, dv.w*rs};
    *(float4*)&ent[base]  = hv;
    *(float4*)&div_[base] = dn;
  }
}

// ---------------- launcher ----------------
extern "C" void kernel_launch(void* const* d_in, const int* in_sizes, int n_in,
                              void* d_out, int out_size, void* d_ws, size_t ws_size,
                              hipStream_t stream){
  const float* x    = (const float*)d_in[0];
  const float* Wk   = (const float*)d_in[1];
  const float* Wq   = (const float*)d_in[2];
  const float* Wv   = (const float*)d_in[3];
  const float* Wout = (const float*)d_in[4];

  float* out     = (float*)d_out;
  float* y_out   = out;
  float* att_out = out + (size_t)TN * DI;
  float* ent_out = att_out + (size_t)TN * TN;
  float* div_out = ent_out + (size_t)TN * TN;
  float* E       = att_out;               // E fp32 in att region until k_epi

  // scratch in ent+div regions (128 MB). Lifetime-disjoint; both regions are
  // overwritten only by k_fill_entdiv at the very end.
  char* S = (char*)ent_out;
  #define MB(x) ((size_t)(x) << 20)
  bf16* xs   = (bf16*)(S + MB(0));    // 16MB [4096][2048] hi|lo, dead after QKV
  bf16* Ws   = (bf16*)(S + MB(16));   // 12MB [3072][2048] hi|lo, dead after QKV
  bf16* Woth = (bf16*)(S + MB(28));   // 2MB
  bf16* xut  = (bf16*)(S + MB(30));   // 8MB
  bf16* Qs   = (bf16*)(S + MB(38));   // 16MB [4096][2048], dead after E
  bf16* Ks   = (bf16*)(S + MB(54));   // 16MB [4096][2048], dead after E
  bf16* Pbf  = (bf16*)(S + MB(38));   // 32MB, overlays Qs+Ks after E
  float* Vb  = (float*)(S + MB(70));  // 16MB
  float* xu  = (float*)(S + MB(86));  // 16MB
  float* cb  = (float*)(S + MB(0));   // 16MB, overlays xs after QKV
  bf16* ym   = (bf16*)(S + MB(102));  // 8MB

  float* ws   = (float*)d_ws;
  float* Hraw = ws;
  float* Hw   = Hraw + TN;
  float* divh = Hw + TN;
  float* dep  = divh + TN;
  float* part = dep + TN;           // 32*DI
  float* stot = part + 32 * DI;     // DI
  float* sums = stot + DI;          // 2

  k_prep<<<dim3(TN), 256, 0, stream>>>(x, xu, xs);
  k_trw<<<dim3(16,16,4), 256, 0, stream>>>(Wq, Wk, Wv, Wout, Ws, Woth);
  k_trx<<<dim3(16,64), 256, 0, stream>>>(xu, xut, TN, DI);
  k_colsum1<<<dim3(4,32), 256, 0, stream>>>(xu, part);
  k_colsum2<<<dim3(4), 256, 0, stream>>>(part, stot);

  // fused QKV (split-3 via K-remap): N=3072; Q,K -> hi/lo; V -> fp32
  k_mfma256<1><<<dim3(12,16), 512, 0, stream>>>(xs, Ws, nullptr, Qs, Ks, Vb);
  // E = Q K^T (split-3 via K-remap) into att region
  k_mfma256<0><<<dim3(16,16), 512, 0, stream>>>(Qs, Ks, E, nullptr, nullptr, nullptr);

  k_rowstats<<<dim3(TN), 256, 0, stream>>>(E, Pbf, Hraw, Hw, divh);
  k_sumvec<<<dim3(1), 256, 0, stream>>>(Hraw, divh, sums);

  // c = P @ xu
  k_mfma<0><<<dim3(8,32), 256, 0, stream>>>(Pbf, xut, TN, TN, DI, TN,
                                            cb, nullptr, nullptr, nullptr, nullptr);

  k_dep<<<dim3(TN), 256, 0, stream>>>(xu, stot, cb, Pbf, dep);
  k_epi<<<dim3(TN), 256, 0, stream>>>(Pbf, dep, Vb, att_out, ym);

  // y = ym @ Wout[:DI] + (Hraw/|Hraw|1)*Wout[DI] + dep*Wout[DI+1]
  k_mfma<2><<<dim3(8,32), 256, 0, stream>>>(ym, Woth, DI, DI, DI, DI,
                                            y_out, Hraw, dep, sums,
                                            Wout + (size_t)DI * DI);

  k_fill_entdiv<<<dim3(TN), 256, 0, stream>>>(Hw, divh, sums, ent_out, div_out);
}

// Round 6
// 457.308 us; speedup vs baseline: 1.0911x; 1.0911x over previous
//
#include <hip/hip_runtime.h>
#include <math.h>
#include <stdint.h>

#define TN   4096
#define DI   1024
#define BSZ  60
#define LOGT 8.317766166719343f
#define EPSV 1e-12f

typedef __bf16 bf16;
typedef bf16  bf16x4 __attribute__((ext_vector_type(4)));
typedef bf16  bf16x8 __attribute__((ext_vector_type(8)));
typedef float f32x4  __attribute__((ext_vector_type(4)));

#define AS1 __attribute__((address_space(1)))
#define AS3 __attribute__((address_space(3)))

__device__ __forceinline__ void gload16(const void* g, void* l){
  __builtin_amdgcn_global_load_lds((AS1 unsigned int*)(uintptr_t)g,
                                   (AS3 unsigned int*)(unsigned int)(uintptr_t)l,
                                   16, 0, 0);
}

// ---------------- reductions ----------------
__device__ __forceinline__ float wsum(float v){
#pragma unroll
  for (int o = 32; o >= 1; o >>= 1) v += __shfl_xor(v, o);
  return v;
}
__device__ __forceinline__ float wmaxr(float v){
#pragma unroll
  for (int o = 32; o >= 1; o >>= 1) v = fmaxf(v, __shfl_xor(v, o));
  return v;
}
__device__ __forceinline__ float bsum(float v, float* sh){
  v = wsum(v);
  if ((threadIdx.x & 63) == 0) sh[threadIdx.x >> 6] = v;
  __syncthreads();
  float r = sh[0] + sh[1] + sh[2] + sh[3];
  __syncthreads();
  return r;
}
__device__ __forceinline__ float bmaxr(float v, float* sh){
  v = wmaxr(v);
  if ((threadIdx.x & 63) == 0) sh[threadIdx.x >> 6] = v;
  __syncthreads();
  float r = fmaxf(fmaxf(sh[0], sh[1]), fmaxf(sh[2], sh[3]));
  __syncthreads();
  return r;
}

// ---------------- prep: xu = normalize(x); xs = [hi|lo] bf16 split (stride 2048) ----------------
__global__ __launch_bounds__(256) void k_prep(const float* __restrict__ x,
                                              float* __restrict__ xu,
                                              bf16* __restrict__ xs){
  __shared__ float sh[4];
  int r = blockIdx.x, tid = threadIdx.x;
  float4 v = ((const float4*)(x + (size_t)r * DI))[tid];
  float ss = v.x*v.x + v.y*v.y + v.z*v.z + v.w*v.w;
  ss = bsum(ss, sh);
  float inv = 1.f / fmaxf(sqrtf(ss), EPSV);
  float4 o = {v.x*inv, v.y*inv, v.z*inv, v.w*inv};
  ((float4*)(xu + (size_t)r * DI))[tid] = o;
  bf16 h0 = (bf16)v.x, h1 = (bf16)v.y, h2 = (bf16)v.z, h3 = (bf16)v.w;
  bf16x4 hv = {h0, h1, h2, h3};
  bf16x4 lv = {(bf16)(v.x-(float)h0), (bf16)(v.y-(float)h1),
               (bf16)(v.z-(float)h2), (bf16)(v.w-(float)h3)};
  *(bf16x4*)&xs[(size_t)r * 2048 + tid * 4]        = hv;
  *(bf16x4*)&xs[(size_t)r * 2048 + 1024 + tid * 4] = lv;
}

// ---------------- fused weight transposes ----------------
__global__ __launch_bounds__(256) void k_trw(const float* __restrict__ W0,
                                             const float* __restrict__ W1,
                                             const float* __restrict__ W2,
                                             const float* __restrict__ W3,
                                             bf16* __restrict__ Ws,
                                             bf16* __restrict__ woth){
  __shared__ float t[64][65];
  int z = blockIdx.z;
  const float* src = (z==0) ? W0 : (z==1) ? W1 : (z==2) ? W2 : W3;
  int c0 = blockIdx.x * 64, r0 = blockIdx.y * 64;
  int tid = threadIdx.x;
  int lr = tid >> 4, lc = (tid & 15) * 4;
#pragma unroll
  for (int p = 0; p < 4; ++p){
    int r = lr + p * 16;
    float4 v = *(const float4*)&src[(size_t)(r0 + r) * DI + c0 + lc];
    t[r][lc+0] = v.x; t[r][lc+1] = v.y; t[r][lc+2] = v.z; t[r][lc+3] = v.w;
  }
  __syncthreads();
#pragma unroll
  for (int p = 0; p < 4; ++p){
    int c = lr + p * 16;
    float v0 = t[lc+0][c], v1 = t[lc+1][c], v2 = t[lc+2][c], v3 = t[lc+3][c];
    bf16 h0 = (bf16)v0, h1 = (bf16)v1, h2 = (bf16)v2, h3 = (bf16)v3;
    bf16x4 hv = {h0, h1, h2, h3};
    if (z < 3){
      bf16* dh = Ws + (size_t)(z * DI + c0 + c) * 2048 + r0 + lc;
      *(bf16x4*)dh = hv;
      bf16x4 lv = {(bf16)(v0-(float)h0), (bf16)(v1-(float)h1),
                   (bf16)(v2-(float)h2), (bf16)(v3-(float)h3)};
      *(bf16x4*)(dh + 1024) = lv;
    } else {
      *(bf16x4*)&woth[(size_t)(c0 + c) * DI + r0 + lc] = hv;
    }
  }
}

// ---------------- transpose fp32 [R][C] -> bf16 [C][R] ----------------
__global__ __launch_bounds__(256) void k_trx(const float* __restrict__ in,
                                             bf16* __restrict__ outh,
                                             int R, int C){
  __shared__ float t[64][65];
  int c0 = blockIdx.x * 64, r0 = blockIdx.y * 64;
  int tid = threadIdx.x;
  int lr = tid >> 4, lc = (tid & 15) * 4;
#pragma unroll
  for (int p = 0; p < 4; ++p){
    int r = lr + p * 16;
    float4 v = *(const float4*)&in[(size_t)(r0 + r) * C + c0 + lc];
    t[r][lc+0] = v.x; t[r][lc+1] = v.y; t[r][lc+2] = v.z; t[r][lc+3] = v.w;
  }
  __syncthreads();
#pragma unroll
  for (int p = 0; p < 4; ++p){
    int c = lr + p * 16;
    bf16x4 hv = {(bf16)t[lc+0][c], (bf16)t[lc+1][c], (bf16)t[lc+2][c], (bf16)t[lc+3][c]};
    *(bf16x4*)&outh[(size_t)(c0 + c) * R + r0 + lc] = hv;
  }
}

// ---------------- column sums of xu ----------------
__global__ __launch_bounds__(256) void k_colsum1(const float* __restrict__ xu,
                                                 float* __restrict__ part){
  int c  = blockIdx.x * 256 + threadIdx.x;
  int r0 = blockIdx.y * 128;
  float s = 0.f;
  for (int r = r0; r < r0 + 128; ++r) s += xu[(size_t)r * DI + c];
  part[(size_t)blockIdx.y * DI + c] = s;
}
__global__ __launch_bounds__(256) void k_colsum2(const float* __restrict__ part,
                                                 float* __restrict__ stot){
  int c = blockIdx.x * 256 + threadIdx.x;
  float s = 0.f;
  for (int b = 0; b < 32; ++b) s += part[(size_t)b * DI + c];
  stot[c] = s;
}

// ================= 256x256 pipelined split-3 MFMA GEMM (counted vmcnt) =================
// A',B' are [rows][2048] = [hi|lo]; K_eff = 3072 via K-tile remap (BK=32, 96 tiles):
//   t<32: Ah*Bh   t<64: Ah*Bl   t<96: Al*Bh
// EPI 0: C fp32 [M][TN] (E).  EPI 1: QKV epilogue (Q,K -> hi/lo split; V -> fp32).
template<int EPI>
__global__ __launch_bounds__(512, 2) void k_mfma256(
    const bf16* __restrict__ A, const bf16* __restrict__ B,
    float* __restrict__ C, bf16* __restrict__ Qs, bf16* __restrict__ Ks,
    float* __restrict__ Vb)
{
  __shared__ alignas(16) bf16 lds[32768];   // 64KB: dbuf × (A 16KB + B 16KB)
  const int tid = threadIdx.x, wid = tid >> 6, lane = tid & 63;
  const int l15 = lane & 15, kb = lane >> 4;
  const int wm = wid >> 2, wn = wid & 3;
  const int row0 = blockIdx.y * 256, col0 = blockIdx.x * 256;

  f32x4 acc[8][4];
  const f32x4 zero = {0.f, 0.f, 0.f, 0.f};
#pragma unroll
  for (int m = 0; m < 8; ++m)
#pragma unroll
    for (int n = 0; n < 4; ++n) acc[m][n] = zero;

  const bf16* Arow = A + (size_t)row0 * 2048;
  const bf16* Brow = B + (size_t)col0 * 2048;

  const int U0 = tid,       r0u = U0 >> 2, c0g = (U0 & 3) ^ ((r0u >> 1) & 3);
  const int U1 = tid + 512, r1u = U1 >> 2, c1g = (U1 & 3) ^ ((r1u >> 1) & 3);
  const int dst0 = (wid * 64) * 8;
  const int dst1 = (512 + wid * 64) * 8;

#define STAGE256(bsel, offA, offB) do{                                        \
    bf16* dA = lds + (bsel) * 16384;                                          \
    bf16* dB = dA + 8192;                                                     \
    gload16(Arow + (size_t)r0u * 2048 + (offA) + c0g * 8, dA + dst0);         \
    gload16(Arow + (size_t)r1u * 2048 + (offA) + c1g * 8, dA + dst1);         \
    gload16(Brow + (size_t)r0u * 2048 + (offB) + c0g * 8, dB + dst0);         \
    gload16(Brow + (size_t)r1u * 2048 + (offB) + c1g * 8, dB + dst1);         \
  }while(0)

  STAGE256(0, 0, 0);     // tile 0 in flight (4 loads)

  for (int t = 0; t < 96; ++t){
    const int buf = t & 1;
    if (t + 1 < 96){
      const int t1 = t + 1;
      const int offA = ((t1 & 31) << 5) + ((t1 >= 64) ? 1024 : 0);
      const int offB = ((t1 & 31) << 5) + ((t1 >= 32 && t1 < 64) ? 1024 : 0);
      STAGE256(buf ^ 1, offA, offB);                  // 8 outstanding
      asm volatile("s_waitcnt vmcnt(4)" ::: "memory"); // tile-t's 4 landed
    } else {
      asm volatile("s_waitcnt vmcnt(0)" ::: "memory");
    }
    __builtin_amdgcn_s_barrier();                     // B1: buf complete for all waves

    const bf16* sA = lds + buf * 16384;
    const bf16* sB = sA + 8192;

    bf16x8 af[8];
#pragma unroll
    for (int m = 0; m < 8; ++m){
      int r = wm * 128 + m * 16 + l15;
      af[m] = *(const bf16x8*)(sA + r * 32 + ((kb ^ ((r >> 1) & 3)) << 3));
    }
#pragma unroll
    for (int half = 0; half < 2; ++half){
      bf16x8 bfr[2];
#pragma unroll
      for (int n = 0; n < 2; ++n){
        int r = wn * 64 + (half * 2 + n) * 16 + l15;
        bfr[n] = *(const bf16x8*)(sB + r * 32 + ((kb ^ ((r >> 1) & 3)) << 3));
      }
      __builtin_amdgcn_s_setprio(1);
#pragma unroll
      for (int m = 0; m < 8; ++m){
        acc[m][half*2+0] = __builtin_amdgcn_mfma_f32_16x16x32_bf16(af[m], bfr[0], acc[m][half*2+0], 0, 0, 0);
        acc[m][half*2+1] = __builtin_amdgcn_mfma_f32_16x16x32_bf16(af[m], bfr[1], acc[m][half*2+1], 0, 0, 0);
      }
      __builtin_amdgcn_s_setprio(0);
    }
    __builtin_amdgcn_s_barrier();                     // B2: all reads of buf done
  }

  const int l4 = lane >> 4;
#pragma unroll
  for (int m = 0; m < 8; ++m){
#pragma unroll
    for (int n = 0; n < 4; ++n){
#pragma unroll
      for (int r = 0; r < 4; ++r){
        int grow = row0 + wm * 128 + m * 16 + l4 * 4 + r;
        int gcol = col0 + wn * 64 + n * 16 + l15;
        float v = acc[m][n][r];
        if constexpr (EPI == 0){
          C[(size_t)grow * TN + gcol] = v;
        } else {
          if (blockIdx.x < 4){
            bf16 h = (bf16)v;
            Qs[(size_t)grow * 2048 + gcol]        = h;
            Qs[(size_t)grow * 2048 + 1024 + gcol] = (bf16)(v - (float)h);
          } else if (blockIdx.x < 8){
            int cc = gcol - 1024;
            bf16 h = (bf16)v;
            Ks[(size_t)grow * 2048 + cc]        = h;
            Ks[(size_t)grow * 2048 + 1024 + cc] = (bf16)(v - (float)h);
          } else {
            Vb[(size_t)grow * DI + (gcol - 2048)] = v;
          }
        }
      }
    }
  }
}

// ---------------- 128x128 MFMA GEMM, triple-buffered counted-vmcnt pipeline ----------------
// C = A[M,K] * Bt[N,K]^T.  EPI 0: fp32 C.  EPI 2: + (ev[row]/max(sums[0],eps))*W12[col] + dv[row]*W12[DI+col]
template<int EPI>
__global__ __launch_bounds__(256) void k_mfma(
    const bf16* __restrict__ Ah, const bf16* __restrict__ Bh,
    int lda, int ldb, int N, int K,
    float* __restrict__ C,
    const float* __restrict__ ev, const float* __restrict__ dv,
    const float* __restrict__ sums, const float* __restrict__ W12)
{
  __shared__ alignas(16) bf16 lds[24576];   // 48KB: 3 bufs × (A 8KB + B 8KB)
  const int tid = threadIdx.x;
  const int wid = tid >> 6;
  const int lane = tid & 63;
  const int row0 = blockIdx.y * 128, col0 = blockIdx.x * 128;
  const int wr = (wid >> 1) * 64, wc = (wid & 1) * 64;
  const int l15 = lane & 15, kb = lane >> 4;

  const int u0 = tid,       r0u = u0 >> 2, k0u = (u0 & 3) ^ ((r0u >> 1) & 3);
  const int u1 = tid + 256, r1u = u1 >> 2, k1u = (u1 & 3) ^ ((r1u >> 1) & 3);
  const int dst0 = (wid * 64) * 8;
  const int dst1 = (256 + wid * 64) * 8;

  f32x4 acc[4][4];
  const f32x4 zero = {0.f, 0.f, 0.f, 0.f};
#pragma unroll
  for (int m = 0; m < 4; ++m)
#pragma unroll
    for (int n = 0; n < 4; ++n) acc[m][n] = zero;

  const bf16* pAh = Ah + (size_t)row0 * lda;
  const bf16* pBh = Bh + (size_t)col0 * ldb;

#define STAGE128(bsel, k0) do{                                       \
    bf16* dA = lds + (bsel) * 8192;                                  \
    bf16* dB = dA + 4096;                                            \
    gload16(pAh + (k0) + (size_t)r0u * lda + k0u * 8, dA + dst0);    \
    gload16(pAh + (k0) + (size_t)r1u * lda + k1u * 8, dA + dst1);    \
    gload16(pBh + (k0) + (size_t)r0u * ldb + k0u * 8, dB + dst0);    \
    gload16(pBh + (k0) + (size_t)r1u * ldb + k1u * 8, dB + dst1);    \
  }while(0)

  const int nk = K >> 5;
  STAGE128(0, 0);
  STAGE128(1, 32);

  for (int it = 0; it < nk; ++it){
    const int buf = it % 3;
    if (it + 2 < nk){
      STAGE128((it + 2) % 3, (it + 2) * 32);           // 12 outstanding
      asm volatile("s_waitcnt vmcnt(8)" ::: "memory"); // tile-it's 4 landed
    } else if (it + 1 < nk){
      asm volatile("s_waitcnt vmcnt(4)" ::: "memory");
    } else {
      asm volatile("s_waitcnt vmcnt(0)" ::: "memory");
    }
    __builtin_amdgcn_s_barrier();

    const bf16* sA = lds + buf * 8192;
    const bf16* sB = sA + 4096;

    bf16x8 bh[4];
#pragma unroll
    for (int n = 0; n < 4; ++n){
      int rr = wc + n * 16 + l15;
      int ss = kb ^ ((rr >> 1) & 3);
      bh[n] = *(const bf16x8*)(sB + (rr * 4 + ss) * 8);
    }
    __builtin_amdgcn_s_setprio(1);
#pragma unroll
    for (int m = 0; m < 4; ++m){
      int rr = wr + m * 16 + l15;
      int ss = kb ^ ((rr >> 1) & 3);
      bf16x8 ah = *(const bf16x8*)(sA + (rr * 4 + ss) * 8);
#pragma unroll
      for (int n = 0; n < 4; ++n)
        acc[m][n] = __builtin_amdgcn_mfma_f32_16x16x32_bf16(ah, bh[n], acc[m][n], 0, 0, 0);
    }
    __builtin_amdgcn_s_setprio(0);
    __builtin_amdgcn_s_barrier();
  }

  const int l4 = lane >> 4;
#pragma unroll
  for (int m = 0; m < 4; ++m){
#pragma unroll
    for (int n = 0; n < 4; ++n){
#pragma unroll
      for (int r = 0; r < 4; ++r){
        int row = row0 + wr + m * 16 + l4 * 4 + r;
        int col = col0 + wc + n * 16 + l15;
        float v = acc[m][n][r];
        if constexpr (EPI == 0){
          C[(size_t)row * N + col] = v;
        } else {
          float en = ev[row] / fmaxf(sums[0], EPSV);
          v += en * W12[col] + dv[row] * W12[DI + col];
          C[(size_t)row * N + col] = v;
        }
      }
    }
  }
}

// ---------------- row stats over E -> P bf16 + Hraw/Hwin/divh ----------------
__global__ __launch_bounds__(256) void k_rowstats(const float* __restrict__ E,
                                                  bf16* __restrict__ Pbf,
                                                  float* __restrict__ Hraw,
                                                  float* __restrict__ Hwin,
                                                  float* __restrict__ divh){
  __shared__ float sh[4];
  int i = blockIdx.x, tid = threadIdx.x;
  const float4* row4 = (const float4*)(E + (size_t)i * TN);
  float4 v[4];
#pragma unroll
  for (int k = 0; k < 4; ++k) v[k] = row4[tid + k * 256];

  int b0 = (i / BSZ) * BSZ;
  int b1 = min(b0 + BSZ, TN);
  int nb = b1 - b0;
  float ewin = -3.4e38f;
  if (tid < 64 && tid < nb) ewin = E[(size_t)i * TN + b0 + tid];

  float mx = -3.4e38f;
#pragma unroll
  for (int k = 0; k < 4; ++k)
    mx = fmaxf(mx, fmaxf(fmaxf(v[k].x, v[k].y), fmaxf(v[k].z, v[k].w)));
  mx = bmaxr(mx, sh);

  float s1 = 0.f, s2 = 0.f;
#pragma unroll
  for (int k = 0; k < 4; ++k){
    float e[4] = {v[k].x, v[k].y, v[k].z, v[k].w};
#pragma unroll
    for (int q = 0; q < 4; ++q){
      float t = e[q] - mx; float w = __expf(t); s1 += w; s2 += w * t;
    }
  }
  s1 = bsum(s1, sh);
  s2 = bsum(s2, sh);
  float rl = 1.f / s1;
  float H  = (__logf(s1) - s2 * rl) / LOGT;

  if (tid < 64){
    float mw = wmaxr(ewin);
    mw = fmaxf(mw, 0.f);
    float t = ewin - mw;
    float w  = (tid < nb) ? __expf(t) : 0.f;
    float wt = (tid < nb) ? w * t     : 0.f;
    float z  = __expf(-mw);
    float s1w = wsum(w)  + (float)(TN - nb) * z;
    float s2w = wsum(wt) + (float)(TN - nb) * z * (-mw);
    if (tid == 0) Hwin[i] = (__logf(s1w) - s2w / s1w) / LOGT;
  }

  float ld = 0.f;
#pragma unroll
  for (int k = 0; k < 4; ++k){
    float e[4] = {v[k].x, v[k].y, v[k].z, v[k].w};
    float p[4];
#pragma unroll
    for (int q = 0; q < 4; ++q){
      p[q] = __expf(e[q] - mx) * rl;
      ld += log1pf(-p[q]);
    }
    bf16x4 pb = {(bf16)p[0], (bf16)p[1], (bf16)p[2], (bf16)p[3]};
    *(bf16x4*)&Pbf[(size_t)i * TN + (size_t)(k * 256 + tid) * 4] = pb;
  }
  ld = bsum(ld, sh);
  if (tid == 0){
    Hraw[i] = H;
    divh[i] = __expf(ld);
  }
}

// ---------------- L1 sums ----------------
__global__ __launch_bounds__(256) void k_sumvec(const float* __restrict__ Hraw,
                                                const float* __restrict__ divh,
                                                float* __restrict__ sums){
  __shared__ float sh[4];
  int tid = threadIdx.x;
  float a = 0.f, b = 0.f;
  for (int i = tid; i < TN; i += 256){ a += fabsf(Hraw[i]); b += fabsf(divh[i]); }
  a = bsum(a, sh);
  b = bsum(b, sh);
  if (tid == 0){ sums[0] = a; sums[1] = b; }
}

// ---------------- dep_factor ----------------
__global__ __launch_bounds__(256) void k_dep(const float* __restrict__ xu,
                                             const float* __restrict__ stot,
                                             const float* __restrict__ cb,
                                             const bf16* __restrict__ Pbf,
                                             float* __restrict__ dep){
  __shared__ float xi[DI];
  __shared__ float sh[4];
  __shared__ float accs[4][3];
  int i = blockIdx.x, tid = threadIdx.x;
  float4 v = ((const float4*)(xu + (size_t)i * DI))[tid];
  ((float4*)xi)[tid] = v;
  float4 s4 = ((const float4*)stot)[tid];
  float4 c4 = ((const float4*)(cb + (size_t)i * DI))[tid];
  float pa = v.x*s4.x + v.y*s4.y + v.z*s4.z + v.w*s4.w;
  float pb = v.x*c4.x + v.y*c4.y + v.z*c4.z + v.w*c4.w;
  float sim_all    = bsum(pa, sh);
  float simatt_all = bsum(pb, sh);

  int b0 = (i / BSZ) * BSZ;
  int b1 = min(b0 + BSZ, TN);
  int nb = b1 - b0;
  int wid = tid >> 6, lane = tid & 63;
  float att_in = 0.f, sim_in = 0.f, simatt_in = 0.f;
  for (int j = b0 + wid; j < b1; j += 4){
    const float* xj = xu + (size_t)j * DI;
    float s = 0.f;
#pragma unroll
    for (int d = 0; d < 16; ++d) s += xi[d * 64 + lane] * xj[d * 64 + lane];
#pragma unroll
    for (int o = 32; o >= 1; o >>= 1) s += __shfl_xor(s, o);
    float att = (float)Pbf[(size_t)i * TN + j];
    att_in += att; sim_in += s; simatt_in += att * s;
  }
  if (lane == 0){ accs[wid][0] = att_in; accs[wid][1] = sim_in; accs[wid][2] = simatt_in; }
  __syncthreads();
  if (tid == 0){
    float a = 0.f, si = 0.f, sa = 0.f;
#pragma unroll
    for (int w = 0; w < 4; ++w){ a += accs[w][0]; si += accs[w][1]; sa += accs[w][2]; }
    float num = (1.f - a) - (simatt_all - sa);
    float den = (float)(TN - nb) - (sim_all - si);
    dep[i] = num / den;
  }
}

// ---------------- epi: att row fill + y_mid, one block per row ----------------
__global__ __launch_bounds__(256) void k_epi(const bf16* __restrict__ Pbf,
                                             const float* __restrict__ dep,
                                             const float* __restrict__ V,
                                             float* __restrict__ att,
                                             bf16* __restrict__ ym){
  __shared__ float w[64];
  int i = blockIdx.x, tid = threadIdx.x;
  int b0 = (i / BSZ) * BSZ;
  int b1 = min(b0 + BSZ, TN);
  int nb = b1 - b0;
  if (tid < nb) w[tid] = (float)Pbf[(size_t)i * TN + b0 + tid] + dep[b0 + tid];
  __syncthreads();

#pragma unroll
  for (int g = 0; g < 4; ++g){
    int c = g * 1024 + tid * 4;
    size_t base = (size_t)i * TN + c;
    float4 av = {0.f, 0.f, 0.f, 0.f};
    if (c + 3 >= b0 && c < b1){
      float t2[4];
#pragma unroll
      for (int q = 0; q < 4; ++q){
        int j = c + q;
        t2[q] = (j >= b0 && j < b1) ? w[j - b0] : 0.f;
      }
      av.x = t2[0]; av.y = t2[1]; av.z = t2[2]; av.w = t2[3];
    }
    *(float4*)&att[base] = av;
  }

  float4 a = {0.f, 0.f, 0.f, 0.f};
  for (int jj = 0; jj < nb; ++jj){
    float wv = w[jj];
    float4 vv = ((const float4*)(V + (size_t)(b0 + jj) * DI))[tid];
    a.x += wv * vv.x; a.y += wv * vv.y; a.z += wv * vv.z; a.w += wv * vv.w;
  }
  bf16x4 o = {(bf16)a.x, (bf16)a.y, (bf16)a.z, (bf16)a.w};
  *(bf16x4*)&ym[(size_t)i * DI + (size_t)tid * 4] = o;
}

// ---------------- ent/div fill (runs LAST; clobbers all big scratch) ----------------
__global__ __launch_bounds__(256) void k_fill_entdiv(const float* __restrict__ Hw,
                                                     const float* __restrict__ divh,
                                                     const float* __restrict__ sums,
                                                     float* __restrict__ ent,
                                                     float* __restrict__ div_){
  int i = blockIdx.x, tid = threadIdx.x;
  float rs = 1.f / sums[1];
#pragma unroll
  for (int g = 0; g < 4; ++g){
    int c = g * 1024 + tid * 4;
    size_t base = (size_t)i * TN + c;
    float4 hv = *(const float4*)&Hw[c];
    float4 dv = *(const float4*)&divh[c];
    float4 dn = {dv.x*rs, dv.y*rs, dv.z*rs, dv.w*rs};
    *(float4*)&ent[base]  = hv;
    *(float4*)&div_[base] = dn;
  }
}

// ---------------- launcher ----------------
extern "C" void kernel_launch(void* const* d_in, const int* in_sizes, int n_in,
                              void* d_out, int out_size, void* d_ws, size_t ws_size,
                              hipStream_t stream){
  const float* x    = (const float*)d_in[0];
  const float* Wk   = (const float*)d_in[1];
  const float* Wq   = (const float*)d_in[2];
  const float* Wv   = (const float*)d_in[3];
  const float* Wout = (const float*)d_in[4];

  float* out     = (float*)d_out;
  float* y_out   = out;
  float* att_out = out + (size_t)TN * DI;
  float* ent_out = att_out + (size_t)TN * TN;
  float* div_out = ent_out + (size_t)TN * TN;
  float* E       = att_out;               // E fp32 in att region until k_epi

  // scratch in ent+div regions (128 MB). Lifetime-disjoint; both regions are
  // overwritten only by k_fill_entdiv at the very end.
  char* S = (char*)ent_out;
  #define MB(x) ((size_t)(x) << 20)
  bf16* xs   = (bf16*)(S + MB(0));    // 16MB [4096][2048] hi|lo, dead after QKV
  bf16* Ws   = (bf16*)(S + MB(16));   // 12MB [3072][2048] hi|lo, dead after QKV
  bf16* Woth = (bf16*)(S + MB(28));   // 2MB
  bf16* xut  = (bf16*)(S + MB(30));   // 8MB
  bf16* Qs   = (bf16*)(S + MB(38));   // 16MB [4096][2048], dead after E
  bf16* Ks   = (bf16*)(S + MB(54));   // 16MB [4096][2048], dead after E
  bf16* Pbf  = (bf16*)(S + MB(38));   // 32MB, overlays Qs+Ks after E
  float* Vb  = (float*)(S + MB(70));  // 16MB
  float* xu  = (float*)(S + MB(86));  // 16MB
  float* cb  = (float*)(S + MB(0));   // 16MB, overlays xs after QKV
  bf16* ym   = (bf16*)(S + MB(102));  // 8MB

  float* ws   = (float*)d_ws;
  float* Hraw = ws;
  float* Hw   = Hraw + TN;
  float* divh = Hw + TN;
  float* dep  = divh + TN;
  float* part = dep + TN;           // 32*DI
  float* stot = part + 32 * DI;     // DI
  float* sums = stot + DI;          // 2

  k_prep<<<dim3(TN), 256, 0, stream>>>(x, xu, xs);
  k_trw<<<dim3(16,16,4), 256, 0, stream>>>(Wq, Wk, Wv, Wout, Ws, Woth);
  k_trx<<<dim3(16,64), 256, 0, stream>>>(xu, xut, TN, DI);
  k_colsum1<<<dim3(4,32), 256, 0, stream>>>(xu, part);
  k_colsum2<<<dim3(4), 256, 0, stream>>>(part, stot);

  // fused QKV (split-3 via K-remap): N=3072; Q,K -> hi/lo; V -> fp32
  k_mfma256<1><<<dim3(12,16), 512, 0, stream>>>(xs, Ws, nullptr, Qs, Ks, Vb);
  // E = Q K^T (split-3 via K-remap) into att region
  k_mfma256<0><<<dim3(16,16), 512, 0, stream>>>(Qs, Ks, E, nullptr, nullptr, nullptr);

  k_rowstats<<<dim3(TN), 256, 0, stream>>>(E, Pbf, Hraw, Hw, divh);
  k_sumvec<<<dim3(1), 256, 0, stream>>>(Hraw, divh, sums);

  // c = P @ xu
  k_mfma<0><<<dim3(8,32), 256, 0, stream>>>(Pbf, xut, TN, TN, DI, TN,
                                            cb, nullptr, nullptr, nullptr, nullptr);

  k_dep<<<dim3(TN), 256, 0, stream>>>(xu, stot, cb, Pbf, dep);
  k_epi<<<dim3(TN), 256, 0, stream>>>(Pbf, dep, Vb, att_out, ym);

  // y = ym @ Wout[:DI] + (Hraw/|Hraw|1)*Wout[DI] + dep*Wout[DI+1]
  k_mfma<2><<<dim3(8,32), 256, 0, stream>>>(ym, Woth, DI, DI, DI, DI,
                                            y_out, Hraw, dep, sums,
                                            Wout + (size_t)DI * DI);

  k_fill_entdiv<<<dim3(TN), 256, 0, stream>>>(Hw, divh, sums, ent_out, div_out);
}